// Round 4
// baseline (1469.295 us; speedup 1.0000x reference)
//
#include <hip/hip_runtime.h>

// TwoDimensionalSSM via direct 2D recurrence. Round 4: the acc[32] array was
// never promoted to VGPRs (SROA runs before loop unrolling; runtime index ->
// alloca stays in scratch -> 2.4 GB spill traffic, VALUBusy 18%). Fix: all
// loops touching acc[] are SOURCE-level unrolled via template recursion, so
// every index is a literal constant at IR-gen time and the first SROA pass
// promotes. Four single-direction sweeps keep peak live regs < 128 cap.
// SiLU epilogue fused into the last (descending) sweep.

#define NPB 8            // images per block (one per 32-lane half, 2/wave)
#define THREADS 256
#define M_TOT 16384      // B*E
#define SCALE 0.70710678118654752f  // sqrt(1/N), N=2

template<int CTRL, int ROW_MASK, bool BC>
__device__ __forceinline__ float dppf(float v) {
    return __int_as_float(__builtin_amdgcn_update_dpp(
        0, __float_as_int(v), CTRL, ROW_MASK, 0xF, BC));
}

__device__ __forceinline__ float sigm(float v) { return 1.0f / (1.0f + __expf(-v)); }

// forward inclusive scan over each 32-lane half: out[j] = sum_{q<=j} a^(j-q) in[q]
__device__ __forceinline__ float scanF(float v, float a, float p2, float p4,
                                       float p8, float w) {
    v = fmaf(a,  dppf<0x111, 0xF, true >(v), v);  // row_shr:1
    v = fmaf(p2, dppf<0x112, 0xF, true >(v), v);  // row_shr:2
    v = fmaf(p4, dppf<0x114, 0xF, true >(v), v);  // row_shr:4
    v = fmaf(p8, dppf<0x118, 0xF, true >(v), v);  // row_shr:8
    v = fmaf(w,  dppf<0x142, 0xA, false>(v), v);  // row_bcast15 -> rows 1,3
    return v;
}

// reverse inclusive scan over each 32-lane half: out[j] = sum_{q>=j} a^(q-j) in[q]
__device__ __forceinline__ float scanR(float v, float a, float p2, float p4,
                                       float p8, float w) {
    v = fmaf(a,  dppf<0x101, 0xF, true>(v), v);   // row_shl:1
    v = fmaf(p2, dppf<0x102, 0xF, true>(v), v);   // row_shl:2
    v = fmaf(p4, dppf<0x104, 0xF, true>(v), v);   // row_shl:4
    v = fmaf(p8, dppf<0x108, 0xF, true>(v), v);   // row_shl:8
    // bit-mode ds_swizzle 0x0200: src = lane16 of each 32-half
    float b = __int_as_float(__builtin_amdgcn_ds_swizzle(__float_as_int(v), 0x0200));
    v = fmaf(w, b, v);
    return v;
}

struct DirP {
    float a1_0, a1_1, p2_0, p2_1, p4_0, p4_1, p8_0, p8_1, w_0, w_1;
    float a2z0, a2z1, ab0, ab1, a3_0, a3_1, a4_0, a4_1;
    float b1_0, b1_1, b2_0, b2_1, a3b1_0, a3b1_1;
    float c1s0, c1s1, c2s0, c2s1, k00;
};

struct SweepSt { float xh0, xh1, xv0, xv1, cx0, cx1, up; };

template<bool REV>
__device__ __forceinline__ void dir_init(DirP& P, int h, int j,
    const float* __restrict__ A1p, const float* __restrict__ A2p,
    const float* __restrict__ A3p, const float* __restrict__ A4p,
    const float* __restrict__ B1p, const float* __restrict__ B2p,
    const float* __restrict__ C1p, const float* __restrict__ C2p)
{
    float2 a1r = *(const float2*)(A1p + 2 * h);
    float2 a2r = *(const float2*)(A2p + 2 * h);
    float2 a3r = *(const float2*)(A3p + 2 * h);
    float2 a4r = *(const float2*)(A4p + 2 * h);
    float2 b1r = *(const float2*)(B1p + 2 * h);
    float2 b2r = *(const float2*)(B2p + 2 * h);
    float2 c1r = *(const float2*)(C1p + 2 * h);
    float2 c2r = *(const float2*)(C2p + 2 * h);
    P.a1_0 = sigm(a1r.x); P.a1_1 = sigm(a1r.y);
    float a2n0 = sigm(a2r.x), a2n1 = sigm(a2r.y);
    P.a3_0 = sigm(a3r.x); P.a3_1 = sigm(a3r.y);
    P.a4_0 = sigm(a4r.x); P.a4_1 = sigm(a4r.y);
    P.b1_0 = sigm(b1r.x); P.b1_1 = sigm(b1r.y);
    P.b2_0 = sigm(b2r.x); P.b2_1 = sigm(b2r.y);
    P.c1s0 = SCALE * c1r.x; P.c1s1 = SCALE * c1r.y;
    P.c2s0 = SCALE * c2r.x; P.c2s1 = SCALE * c2r.y;
    P.k00  = P.c1s0 * P.b1_0 + P.c1s1 * P.b1_1 + P.c2s0 * P.b2_0 + P.c2s1 * P.b2_1;
    // boundary kill: fwd at j==0 (also kills wave_shr cross-half leak),
    // rev at j==31 (kills wave_shl cross-half leak)
    const bool edge = REV ? (j == 31) : (j == 0);
    P.a2z0 = edge ? 0.f : a2n0;
    P.a2z1 = edge ? 0.f : a2n1;
    P.ab0  = P.a2z0 * P.b2_0; P.ab1 = P.a2z1 * P.b2_1;
    P.a3b1_0 = P.a3_0 * P.b1_0; P.a3b1_1 = P.a3_1 * P.b1_1;
    P.p2_0 = P.a1_0 * P.a1_0; P.p4_0 = P.p2_0 * P.p2_0; P.p8_0 = P.p4_0 * P.p4_0;
    P.p2_1 = P.a1_1 * P.a1_1; P.p4_1 = P.p2_1 * P.p2_1; P.p8_1 = P.p4_1 * P.p4_1;
    if (REV) {
        P.w_0 = ((j & 16) == 0) ? __powf(P.a1_0, (float)(16 - (j & 15))) : 0.f;
        P.w_1 = ((j & 16) == 0) ? __powf(P.a1_1, (float)(16 - (j & 15))) : 0.f;
    } else {
        P.w_0 = __powf(P.a1_0, (float)((j & 15) + 1));
        P.w_1 = __powf(P.a1_1, (float)((j & 15) + 1));
    }
}

template<bool REV>
__device__ __forceinline__ float dir_step(const DirP& P, float u, SweepSt& st)
{
    float b2u0 = P.b2_0 * u, b2u1 = P.b2_1 * u;
    float nxv0 = fmaf(P.a3_0, st.xh0, fmaf(P.a4_0, st.xv0, b2u0));
    float nxv1 = fmaf(P.a3_1, st.xh1, fmaf(P.a4_1, st.xv1, b2u1));
    float ncx0 = fmaf(P.a3b1_0, st.up, fmaf(P.a4_0, st.cx0, b2u0));
    float ncx1 = fmaf(P.a3b1_1, st.up, fmaf(P.a4_1, st.cx1, b2u1));
    float xl0, xl1, ul;
    if (REV) {   // neighbor = column j+1 -> wave_shl:1
        xl0 = dppf<0x130, 0xF, true>(nxv0);
        xl1 = dppf<0x130, 0xF, true>(nxv1);
        ul  = dppf<0x130, 0xF, true>(u);
    } else {     // neighbor = column j-1 -> wave_shr:1
        xl0 = dppf<0x138, 0xF, true>(nxv0);
        xl1 = dppf<0x138, 0xF, true>(nxv1);
        ul  = dppf<0x138, 0xF, true>(u);
    }
    float b1u0 = P.b1_0 * u, b1u1 = P.b1_1 * u;
    float d0 = fmaf(P.a2z0, xl0, b1u0);
    float d1 = fmaf(P.a2z1, xl1, b1u1);
    float e0 = fmaf(P.ab0, ul, b1u0);
    float e1 = fmaf(P.ab1, ul, b1u1);
    float nh0, nh1, rh0, rh1;
    if (REV) {
        nh0 = scanR(d0, P.a1_0, P.p2_0, P.p4_0, P.p8_0, P.w_0);
        nh1 = scanR(d1, P.a1_1, P.p2_1, P.p4_1, P.p8_1, P.w_1);
        rh0 = scanR(e0, P.a1_0, P.p2_0, P.p4_0, P.p8_0, P.w_0);
        rh1 = scanR(e1, P.a1_1, P.p2_1, P.p4_1, P.p8_1, P.w_1);
    } else {
        nh0 = scanF(d0, P.a1_0, P.p2_0, P.p4_0, P.p8_0, P.w_0);
        nh1 = scanF(d1, P.a1_1, P.p2_1, P.p4_1, P.p8_1, P.w_1);
        rh0 = scanF(e0, P.a1_0, P.p2_0, P.p4_0, P.p8_0, P.w_0);
        rh1 = scanF(e1, P.a1_1, P.p2_1, P.p4_1, P.p8_1, P.w_1);
    }
    float y = fmaf(P.c1s0, nh0 + rh0, fmaf(P.c1s1, nh1 + rh1,
              fmaf(P.c2s0, nxv0 + ncx0, fmaf(P.c2s1, nxv1 + ncx1, -P.k00 * u))));
    st.xh0 = nh0; st.xh1 = nh1; st.xv0 = nxv0; st.xv1 = nxv1;
    st.cx0 = ncx0; st.cx1 = ncx1; st.up = u;
    return y;
}

// Source-level unrolled sweep: S is a template parameter, so acc[row] is a
// CONSTANT GEP at IR-gen time -> first SROA pass promotes acc to VGPRs.
// MODE: 0 = first sweep (init acc + residual), 1 = accumulate,
//       2 = last sweep (accumulate + fused SiLU + LDS writeback).
template<int S, bool REV, bool DESC, int MODE>
__device__ __forceinline__ void sweep(const DirP& P, float* uim, int colx,
                                      float om, float (&acc)[32], SweepSt& st)
{
    if constexpr (S < 32) {
        constexpr int row = DESC ? (31 - S) : S;
        float u = uim[row * 32 + colx];
        float y = dir_step<REV>(P, u, st);
        if constexpr (MODE == 0) {
            acc[row] = fmaf(u, om, y);          // residual folded here
        } else if constexpr (MODE == 1) {
            acc[row] += y;
        } else {
            float z = acc[row] + y;
            float sg = 1.0f / (1.0f + __expf(-z));
            uim[row * 32 + colx] = z * sg;      // row fully consumed: overwrite ok
        }
        sweep<S + 1, REV, DESC, MODE>(P, uim, colx, om, acc, st);
    }
}

__global__ __launch_bounds__(THREADS, 4) void ssm2d_kernel(
    const float* __restrict__ x,
    const float* __restrict__ A1p, const float* __restrict__ A2p,
    const float* __restrict__ A3p, const float* __restrict__ A4p,
    const float* __restrict__ B1p, const float* __restrict__ B2p,
    const float* __restrict__ C1p, const float* __restrict__ C2p,
    const float* __restrict__ omega,
    float* __restrict__ out)
{
    __shared__ float u_lds[NPB * 1024];   // 32 KB; XOR-swizzled addressing
    const int t = threadIdx.x;
    // XCD-aware remap: blocks on the same XCD (bid%8 fixed) cover adjacent
    // m-ranges so both halves of each 64B x-line hit the same L2.
    const int bid = blockIdx.x;
    const int m0  = ((bid & 7) * 256 + (bid >> 3)) * NPB;

    // ---- stage x into LDS; XOR swizzle (pix ^ 4*img) kills 8-way conflicts ----
    const int simg = t & 7;
    #pragma unroll 4
    for (int it = 0; it < 32; ++it) {
        int pix = it * 32 + (t >> 3);
        u_lds[simg * 1024 + (pix ^ (simg << 2))] = x[(size_t)pix * M_TOT + (m0 + simg)];
    }
    __syncthreads();

    const int j   = t & 31;
    const int img = t >> 5;
    const int m   = m0 + img;
    const int colx = j ^ (img << 2);      // per-lane LDS column (bank-distinct)
    float* uim = u_lds + img * 1024;
    const float om = omega[m & 1023];
    const int hb = m & 63;

    float acc[32];   // promoted to VGPRs: all accesses are template-constant

    {   // d0: rows ascending, forward scan (init + residual)
        DirP P; dir_init<false>(P, hb, j, A1p, A2p, A3p, A4p, B1p, B2p, C1p, C2p);
        SweepSt st{};
        sweep<0, false, false, 0>(P, uim, colx, om, acc, st);
    }
    {   // d2: rows ascending, reverse scan
        DirP P; dir_init<true>(P, 128 + hb, j, A1p, A2p, A3p, A4p, B1p, B2p, C1p, C2p);
        SweepSt st{};
        sweep<0, true, false, 1>(P, uim, colx, om, acc, st);
    }
    {   // d1: rows descending, forward scan
        DirP P; dir_init<false>(P, 64 + hb, j, A1p, A2p, A3p, A4p, B1p, B2p, C1p, C2p);
        SweepSt st{};
        sweep<0, false, true, 1>(P, uim, colx, om, acc, st);
    }
    {   // d3: rows descending, reverse scan + fused SiLU + LDS writeback
        DirP P; dir_init<true>(P, 192 + hb, j, A1p, A2p, A3p, A4p, B1p, B2p, C1p, C2p);
        SweepSt st{};
        sweep<0, true, true, 2>(P, uim, colx, om, acc, st);
    }
    __syncthreads();

    // ---- coalesced store-out ----
    #pragma unroll 4
    for (int it = 0; it < 32; ++it) {
        int pix = it * 32 + (t >> 3);
        out[(size_t)pix * M_TOT + (m0 + simg)] =
            u_lds[simg * 1024 + (pix ^ (simg << 2))];
    }
}

extern "C" void kernel_launch(void* const* d_in, const int* in_sizes, int n_in,
                              void* d_out, int out_size, void* d_ws, size_t ws_size,
                              hipStream_t stream) {
    const float* x  = (const float*)d_in[0];
    const float* A1 = (const float*)d_in[1];
    const float* A2 = (const float*)d_in[2];
    const float* A3 = (const float*)d_in[3];
    const float* A4 = (const float*)d_in[4];
    const float* B1 = (const float*)d_in[5];
    const float* B2 = (const float*)d_in[6];
    const float* C1 = (const float*)d_in[7];
    const float* C2 = (const float*)d_in[8];
    const float* om = (const float*)d_in[9];
    float* out = (float*)d_out;
    hipLaunchKernelGGL(ssm2d_kernel, dim3(M_TOT / NPB), dim3(THREADS), 0, stream,
                       x, A1, A2, A3, A4, B1, B2, C1, C2, om, out);
}